// Round 1
// baseline (749.094 us; speedup 1.0000x reference)
//
#include <hip/hip_runtime.h>
#include <hip/hip_bf16.h>

#define N_NODES 100000
#define N_EDGES 1600000
#define F_IN 20
#define HID 64
#define N_GRAPHS 2000

// ---------------- CSR build ----------------

__global__ void k_deg(const int* __restrict__ dst, int* __restrict__ cnt) {
    int e = blockIdx.x * 256 + threadIdx.x;
    if (e < N_EDGES) atomicAdd(&cnt[dst[e]], 1);
}

__global__ void k_dinv(const int* __restrict__ cnt, float* __restrict__ dinv) {
    int v = blockIdx.x * 256 + threadIdx.x;
    if (v < N_NODES) dinv[v] = 1.0f / sqrtf((float)(cnt[v] + 1));  // +1 self-loop
}

// block handles 1024 elements (tid*4 consecutive), exclusive scan
__global__ void k_scan1(const int* __restrict__ in, int* __restrict__ out,
                        int* __restrict__ partials) {
    __shared__ int lds[256];
    int tid = threadIdx.x;
    int base = blockIdx.x * 1024 + tid * 4;
    int v0 = (base + 0 < N_NODES) ? in[base + 0] : 0;
    int v1 = (base + 1 < N_NODES) ? in[base + 1] : 0;
    int v2 = (base + 2 < N_NODES) ? in[base + 2] : 0;
    int v3 = (base + 3 < N_NODES) ? in[base + 3] : 0;
    int tsum = v0 + v1 + v2 + v3;
    lds[tid] = tsum;
    __syncthreads();
    for (int off = 1; off < 256; off <<= 1) {
        int t = (tid >= off) ? lds[tid - off] : 0;
        __syncthreads();
        lds[tid] += t;
        __syncthreads();
    }
    int excl = lds[tid] - tsum;
    if (base + 0 < N_NODES) out[base + 0] = excl;
    if (base + 1 < N_NODES) out[base + 1] = excl + v0;
    if (base + 2 < N_NODES) out[base + 2] = excl + v0 + v1;
    if (base + 3 < N_NODES) out[base + 3] = excl + v0 + v1 + v2;
    if (tid == 255) partials[blockIdx.x] = lds[255];
}

__global__ void k_scan2(int* __restrict__ partials, int nb) {
    __shared__ int lds[256];
    int tid = threadIdx.x;
    int v = (tid < nb) ? partials[tid] : 0;
    lds[tid] = v;
    __syncthreads();
    for (int off = 1; off < 256; off <<= 1) {
        int t = (tid >= off) ? lds[tid - off] : 0;
        __syncthreads();
        lds[tid] += t;
        __syncthreads();
    }
    if (tid < nb) partials[tid] = lds[tid] - v;  // exclusive
}

__global__ void k_scan3(int* __restrict__ row_ptr, int* __restrict__ cursor,
                        const int* __restrict__ partials) {
    int idx = blockIdx.x * 256 + threadIdx.x;
    if (idx < N_NODES) {
        int r = row_ptr[idx] + partials[idx >> 10];
        row_ptr[idx] = r;
        cursor[idx] = r;
    }
    if (idx == 0) row_ptr[N_NODES] = N_EDGES;
}

__global__ void k_fill(const int* __restrict__ src, const int* __restrict__ dst,
                       int* __restrict__ cursor, int* __restrict__ col) {
    int e = blockIdx.x * 256 + threadIdx.x;
    if (e < N_EDGES) {
        int d = dst[e];
        int pos = atomicAdd(&cursor[d], 1);
        col[pos] = src[e];
    }
}

// ---------------- layers ----------------

// y[v,:] = dinv[v] * (x[v,:] @ W)   for F_IN=20 input
__global__ __launch_bounds__(256) void k_gemm1(const float* __restrict__ x,
                                               const float* __restrict__ W,
                                               const float* __restrict__ dinv,
                                               float* __restrict__ y) {
    __shared__ float Ws[F_IN * HID];
    int tid = threadIdx.x;
    for (int i = tid; i < F_IN * HID; i += 256) Ws[i] = W[i];
    __syncthreads();
    int v = blockIdx.x * 4 + (tid >> 6);
    int lane = tid & 63;
    float xv = (lane < F_IN) ? x[v * F_IN + lane] : 0.0f;
    float acc = 0.0f;
#pragma unroll
    for (int k = 0; k < F_IN; ++k) {
        acc += __shfl(xv, k) * Ws[k * HID + lane];
    }
    y[v * HID + lane] = dinv[v] * acc;
}

// y[v,:] = dinv[v] * (hin[v,:] @ W)  for HID=64 input
__global__ __launch_bounds__(256) void k_gemm64(const float* __restrict__ hin,
                                                const float* __restrict__ W,
                                                const float* __restrict__ dinv,
                                                float* __restrict__ y) {
    __shared__ float Ws[HID * HID];
    int tid = threadIdx.x;
#pragma unroll
    for (int i = 0; i < 16; ++i) Ws[tid + i * 256] = W[tid + i * 256];
    __syncthreads();
    int v = blockIdx.x * 4 + (tid >> 6);
    int lane = tid & 63;
    float hv = hin[v * HID + lane];
    float acc = 0.0f;
#pragma unroll
    for (int k = 0; k < HID; ++k) {
        acc += __shfl(hv, k) * Ws[k * HID + lane];
    }
    y[v * HID + lane] = dinv[v] * acc;
}

// h[v,:] = relu(dinv[v] * (sum_{s in CSR row v} y[s,:] + y[v,:]) + b)
__global__ __launch_bounds__(256) void k_agg(const float* __restrict__ y,
                                             const int* __restrict__ row_ptr,
                                             const int* __restrict__ col,
                                             const float* __restrict__ dinv,
                                             const float* __restrict__ b,
                                             float* __restrict__ hout) {
    int tid = threadIdx.x;
    int v = blockIdx.x * 4 + (tid >> 6);
    int lane = tid & 63;
    int e = row_ptr[v];
    int eEnd = row_ptr[v + 1];
    float acc = y[v * HID + lane];  // self-loop contribution
    for (; e + 4 <= eEnd; e += 4) {
        int s0 = col[e], s1 = col[e + 1], s2 = col[e + 2], s3 = col[e + 3];
        float a0 = y[s0 * HID + lane];
        float a1 = y[s1 * HID + lane];
        float a2 = y[s2 * HID + lane];
        float a3 = y[s3 * HID + lane];
        acc += a0;
        acc += a1;
        acc += a2;
        acc += a3;
    }
    for (; e < eEnd; ++e) acc += y[col[e] * HID + lane];
    float r = dinv[v] * acc + b[lane];
    hout[v * HID + lane] = fmaxf(r, 0.0f);
}

// ---------------- pool + head (one wave per graph) ----------------

__device__ __forceinline__ int lower_bound(const int* __restrict__ a, int n, int key) {
    int lo = 0, hi = n;
    while (lo < hi) {
        int mid = (lo + hi) >> 1;
        if (a[mid] < key) lo = mid + 1; else hi = mid;
    }
    return lo;
}

__global__ __launch_bounds__(64) void k_pool_head(const float* __restrict__ h,
                                                  const int* __restrict__ batch,
                                                  const float* __restrict__ lw1,
                                                  const float* __restrict__ lb1,
                                                  const float* __restrict__ lw2,
                                                  const float* __restrict__ lb2,
                                                  float* __restrict__ out) {
    int g = blockIdx.x;
    int lane = threadIdx.x;
    int lo = lower_bound(batch, N_NODES, g);
    int hi = lower_bound(batch, N_NODES, g + 1);
    float s = 0.0f;
    for (int v = lo; v < hi; ++v) s += h[v * HID + lane];
    float gm = s / fmaxf((float)(hi - lo), 1.0f);
    float acc = lb1[lane];
#pragma unroll
    for (int k = 0; k < HID; ++k) {
        acc += __shfl(gm, k) * lw1[k * HID + lane];
    }
    float t1 = fmaxf(acc, 0.0f);
    float r = t1 * lw2[lane];
#pragma unroll
    for (int off = 32; off > 0; off >>= 1) r += __shfl_xor(r, off);
    if (lane == 0) out[g] = r + lb2[0];
}

// ---------------- launch ----------------

extern "C" void kernel_launch(void* const* d_in, const int* in_sizes, int n_in,
                              void* d_out, int out_size, void* d_ws, size_t ws_size,
                              hipStream_t stream) {
    const float* x   = (const float*)d_in[0];
    const float* W1  = (const float*)d_in[1];
    const float* b1  = (const float*)d_in[2];
    const float* W2  = (const float*)d_in[3];
    const float* b2  = (const float*)d_in[4];
    const float* W3  = (const float*)d_in[5];
    const float* b3  = (const float*)d_in[6];
    const float* lw1 = (const float*)d_in[7];
    const float* lb1 = (const float*)d_in[8];
    const float* lw2 = (const float*)d_in[9];
    const float* lb2 = (const float*)d_in[10];
    const int* ei    = (const int*)d_in[11];
    const int* batch = (const int*)d_in[12];
    const int* src = ei;             // edge_index[0]
    const int* dst = ei + N_EDGES;   // edge_index[1]
    float* out = (float*)d_out;

    // workspace layout (int/float units, 4B each)
    int* ws = (int*)d_ws;
    int* row_cnt = ws;                       // [100352]  (zeroed)
    int* row_ptr = ws + 100352;              // [100352]
    int* cursor  = ws + 200704;              // [100352]
    int* col     = ws + 301056;              // [1600000]
    float* dinv  = (float*)(ws + 1901056);   // [100352]
    float* y     = (float*)(ws + 2001408);   // [6400000]
    float* h     = (float*)(ws + 8401408);   // [6400000]
    int* partials = ws + 14801408;           // [256]

    hipMemsetAsync(row_cnt, 0, 100352 * sizeof(int), stream);

    k_deg<<<N_EDGES / 256, 256, 0, stream>>>(dst, row_cnt);
    k_dinv<<<(N_NODES + 255) / 256, 256, 0, stream>>>(row_cnt, dinv);
    k_scan1<<<98, 256, 0, stream>>>(row_cnt, row_ptr, partials);
    k_scan2<<<1, 256, 0, stream>>>(partials, 98);
    k_scan3<<<(N_NODES + 255) / 256, 256, 0, stream>>>(row_ptr, cursor, partials);
    k_fill<<<N_EDGES / 256, 256, 0, stream>>>(src, dst, cursor, col);

    // layer 1: x(20) -> h(64)
    k_gemm1<<<N_NODES / 4, 256, 0, stream>>>(x, W1, dinv, y);
    k_agg<<<N_NODES / 4, 256, 0, stream>>>(y, row_ptr, col, dinv, b1, h);
    // layer 2
    k_gemm64<<<N_NODES / 4, 256, 0, stream>>>(h, W2, dinv, y);
    k_agg<<<N_NODES / 4, 256, 0, stream>>>(y, row_ptr, col, dinv, b2, h);
    // layer 3
    k_gemm64<<<N_NODES / 4, 256, 0, stream>>>(h, W3, dinv, y);
    k_agg<<<N_NODES / 4, 256, 0, stream>>>(y, row_ptr, col, dinv, b3, h);

    // pool + head
    k_pool_head<<<N_GRAPHS, 64, 0, stream>>>(h, batch, lw1, lb1, lw2, lb2, out);
}

// Round 3
// 626.939 us; speedup vs baseline: 1.1948x; 1.1948x over previous
//
#include <hip/hip_runtime.h>
#include <hip/hip_bf16.h>

#define N_NODES 100000
#define N_EDGES 1600000
#define F_IN 20
#define HID 64
#define N_GRAPHS 2000

#define RNG 8           // node ranges == XCD count
#define RANGE_SZ 12500  // N_NODES / RNG
#define EPB 6400        // edges per block chunk
#define NCHUNK 250      // N_EDGES / EPB

// ---------------- CSR build (range-filtered, XCD-local) ----------------

// grid = NCHUNK * RNG; blockIdx % 8 selects range -> lands on XCD (range) under
// round-robin dispatch, so all atomics/writes for a range stay in ONE L2.
__global__ __launch_bounds__(256) void k_deg_f(const int* __restrict__ dst,
                                               int* __restrict__ cnt) {
    int r = blockIdx.x & (RNG - 1);
    int c = blockIdx.x >> 3;
    int lo = r * RANGE_SZ, hi = lo + RANGE_SZ;
    int base = c * EPB;
    for (int i = threadIdx.x; i < EPB; i += 256) {
        int d = dst[base + i];
        if (d >= lo && d < hi) atomicAdd(&cnt[d], 1);
    }
}

__global__ __launch_bounds__(256) void k_fill_f(const int* __restrict__ src,
                                                const int* __restrict__ dst,
                                                int* __restrict__ cursor,
                                                int* __restrict__ col) {
    int r = blockIdx.x & (RNG - 1);
    int c = blockIdx.x >> 3;
    int lo = r * RANGE_SZ, hi = lo + RANGE_SZ;
    int base = c * EPB;
    for (int i = threadIdx.x; i < EPB; i += 256) {
        int e = base + i;
        int d = dst[e];
        if (d >= lo && d < hi) {
            int pos = atomicAdd(&cursor[d], 1);
            col[pos] = src[e];
        }
    }
}

// block scans 1024 elements; also emits dinv = 1/sqrt(deg+1)
__global__ void k_scan1(const int* __restrict__ in, int* __restrict__ out,
                        int* __restrict__ partials, float* __restrict__ dinv) {
    __shared__ int lds[256];
    int tid = threadIdx.x;
    int base = blockIdx.x * 1024 + tid * 4;
    int v0 = (base + 0 < N_NODES) ? in[base + 0] : 0;
    int v1 = (base + 1 < N_NODES) ? in[base + 1] : 0;
    int v2 = (base + 2 < N_NODES) ? in[base + 2] : 0;
    int v3 = (base + 3 < N_NODES) ? in[base + 3] : 0;
    if (base + 0 < N_NODES) dinv[base + 0] = 1.0f / sqrtf((float)(v0 + 1));
    if (base + 1 < N_NODES) dinv[base + 1] = 1.0f / sqrtf((float)(v1 + 1));
    if (base + 2 < N_NODES) dinv[base + 2] = 1.0f / sqrtf((float)(v2 + 1));
    if (base + 3 < N_NODES) dinv[base + 3] = 1.0f / sqrtf((float)(v3 + 1));
    int tsum = v0 + v1 + v2 + v3;
    lds[tid] = tsum;
    __syncthreads();
    for (int off = 1; off < 256; off <<= 1) {
        int t = (tid >= off) ? lds[tid - off] : 0;
        __syncthreads();
        lds[tid] += t;
        __syncthreads();
    }
    int excl = lds[tid] - tsum;
    if (base + 0 < N_NODES) out[base + 0] = excl;
    if (base + 1 < N_NODES) out[base + 1] = excl + v0;
    if (base + 2 < N_NODES) out[base + 2] = excl + v0 + v1;
    if (base + 3 < N_NODES) out[base + 3] = excl + v0 + v1 + v2;
    if (tid == 255) partials[blockIdx.x] = lds[255];
}

__global__ void k_scan2(int* __restrict__ partials, int nb) {
    __shared__ int lds[256];
    int tid = threadIdx.x;
    int v = (tid < nb) ? partials[tid] : 0;
    lds[tid] = v;
    __syncthreads();
    for (int off = 1; off < 256; off <<= 1) {
        int t = (tid >= off) ? lds[tid - off] : 0;
        __syncthreads();
        lds[tid] += t;
        __syncthreads();
    }
    if (tid < nb) partials[tid] = lds[tid] - v;  // exclusive
}

__global__ void k_scan3(int* __restrict__ row_ptr, int* __restrict__ cursor,
                        const int* __restrict__ partials) {
    int idx = blockIdx.x * 256 + threadIdx.x;
    if (idx < N_NODES) {
        int r = row_ptr[idx] + partials[idx >> 10];
        row_ptr[idx] = r;
        cursor[idx] = r;
    }
    if (idx == 0) row_ptr[N_NODES] = N_EDGES;
}

// ---------------- layers ----------------

// y[v,:] = dinv[v] * (x[v,:] @ W)   (F_IN=20 input)
__global__ __launch_bounds__(256) void k_gemm1(const float* __restrict__ x,
                                               const float* __restrict__ W,
                                               const float* __restrict__ dinv,
                                               float* __restrict__ y) {
    __shared__ float Ws[F_IN * HID];
    int tid = threadIdx.x;
    for (int i = tid; i < F_IN * HID; i += 256) Ws[i] = W[i];
    __syncthreads();
    int v = blockIdx.x * 4 + (tid >> 6);
    int lane = tid & 63;
    float xv = (lane < F_IN) ? x[v * F_IN + lane] : 0.0f;
    float acc = 0.0f;
#pragma unroll
    for (int k = 0; k < F_IN; ++k) acc += __shfl(xv, k) * Ws[k * HID + lane];
    y[v * HID + lane] = dinv[v] * acc;
}

// fused: h = relu(dinv*(gather-sum + self) + b);  ynext = dinv * (h @ W)
__global__ __launch_bounds__(256) void k_aggemm(const float* __restrict__ y,
                                                const int* __restrict__ row_ptr,
                                                const int* __restrict__ col,
                                                const float* __restrict__ dinv,
                                                const float* __restrict__ b,
                                                const float* __restrict__ W,
                                                float* __restrict__ ynext) {
    __shared__ float Ws[HID * HID];
    int tid = threadIdx.x;
#pragma unroll
    for (int i = 0; i < 16; ++i) Ws[tid + i * 256] = W[tid + i * 256];
    __syncthreads();
    int v = blockIdx.x * 4 + (tid >> 6);
    int lane = tid & 63;
    int e = row_ptr[v], eEnd = row_ptr[v + 1];
    float acc = y[v * HID + lane];  // self-loop
    for (; e + 8 <= eEnd; e += 8) {
        int s0 = col[e], s1 = col[e + 1], s2 = col[e + 2], s3 = col[e + 3];
        int s4 = col[e + 4], s5 = col[e + 5], s6 = col[e + 6], s7 = col[e + 7];
        float a0 = y[s0 * HID + lane], a1 = y[s1 * HID + lane];
        float a2 = y[s2 * HID + lane], a3 = y[s3 * HID + lane];
        float a4 = y[s4 * HID + lane], a5 = y[s5 * HID + lane];
        float a6 = y[s6 * HID + lane], a7 = y[s7 * HID + lane];
        acc += a0 + a1 + a2 + a3 + a4 + a5 + a6 + a7;
    }
    for (; e < eEnd; ++e) acc += y[col[e] * HID + lane];
    float h = fmaxf(dinv[v] * acc + b[lane], 0.0f);
    float o = 0.0f;
#pragma unroll
    for (int k = 0; k < HID; ++k) o += __shfl(h, k) * Ws[k * HID + lane];
    ynext[v * HID + lane] = dinv[v] * o;
}

// final layer: h = relu(dinv*(gather-sum + self) + b)
__global__ __launch_bounds__(256) void k_agg(const float* __restrict__ y,
                                             const int* __restrict__ row_ptr,
                                             const int* __restrict__ col,
                                             const float* __restrict__ dinv,
                                             const float* __restrict__ b,
                                             float* __restrict__ hout) {
    int tid = threadIdx.x;
    int v = blockIdx.x * 4 + (tid >> 6);
    int lane = tid & 63;
    int e = row_ptr[v], eEnd = row_ptr[v + 1];
    float acc = y[v * HID + lane];
    for (; e + 8 <= eEnd; e += 8) {
        int s0 = col[e], s1 = col[e + 1], s2 = col[e + 2], s3 = col[e + 3];
        int s4 = col[e + 4], s5 = col[e + 5], s6 = col[e + 6], s7 = col[e + 7];
        float a0 = y[s0 * HID + lane], a1 = y[s1 * HID + lane];
        float a2 = y[s2 * HID + lane], a3 = y[s3 * HID + lane];
        float a4 = y[s4 * HID + lane], a5 = y[s5 * HID + lane];
        float a6 = y[s6 * HID + lane], a7 = y[s7 * HID + lane];
        acc += a0 + a1 + a2 + a3 + a4 + a5 + a6 + a7;
    }
    for (; e < eEnd; ++e) acc += y[col[e] * HID + lane];
    float r = dinv[v] * acc + b[lane];
    hout[v * HID + lane] = fmaxf(r, 0.0f);
}

// ---------------- pool + head ----------------

__device__ __forceinline__ int lower_bound(const int* __restrict__ a, int n, int key) {
    int lo = 0, hi = n;
    while (lo < hi) {
        int mid = (lo + hi) >> 1;
        if (a[mid] < key) lo = mid + 1; else hi = mid;
    }
    return lo;
}

__global__ __launch_bounds__(64) void k_pool_head(const float* __restrict__ h,
                                                  const int* __restrict__ batch,
                                                  const float* __restrict__ lw1,
                                                  const float* __restrict__ lb1,
                                                  const float* __restrict__ lw2,
                                                  const float* __restrict__ lb2,
                                                  float* __restrict__ out) {
    int g = blockIdx.x;
    int lane = threadIdx.x;
    int lo = lower_bound(batch, N_NODES, g);
    int hi = lower_bound(batch, N_NODES, g + 1);
    float s = 0.0f;
    for (int v = lo; v < hi; ++v) s += h[v * HID + lane];
    float gm = s / fmaxf((float)(hi - lo), 1.0f);
    float acc = lb1[lane];
#pragma unroll
    for (int k = 0; k < HID; ++k) acc += __shfl(gm, k) * lw1[k * HID + lane];
    float t1 = fmaxf(acc, 0.0f);
    float r = t1 * lw2[lane];
#pragma unroll
    for (int off = 32; off > 0; off >>= 1) r += __shfl_xor(r, off);
    if (lane == 0) out[g] = r + lb2[0];
}

// ---------------- launch ----------------

extern "C" void kernel_launch(void* const* d_in, const int* in_sizes, int n_in,
                              void* d_out, int out_size, void* d_ws, size_t ws_size,
                              hipStream_t stream) {
    const float* x   = (const float*)d_in[0];
    const float* W1  = (const float*)d_in[1];
    const float* b1  = (const float*)d_in[2];
    const float* W2  = (const float*)d_in[3];
    const float* b2  = (const float*)d_in[4];
    const float* W3  = (const float*)d_in[5];
    const float* b3  = (const float*)d_in[6];
    const float* lw1 = (const float*)d_in[7];
    const float* lb1 = (const float*)d_in[8];
    const float* lw2 = (const float*)d_in[9];
    const float* lb2 = (const float*)d_in[10];
    const int* ei    = (const int*)d_in[11];
    const int* batch = (const int*)d_in[12];
    const int* src = ei;             // edge_index[0]
    const int* dst = ei + N_EDGES;   // edge_index[1]
    float* out = (float*)d_out;

    // workspace layout (4B units) — same footprint as R1 (passed)
    int* ws = (int*)d_ws;
    int* row_cnt = ws;                       // [100352]  (zeroed)
    int* row_ptr = ws + 100352;              // [100353]
    int* cursor  = ws + 200704;              // [100352]
    int* col     = ws + 301056;              // [1600000]
    float* dinv  = (float*)(ws + 1901056);   // [100352]
    float* bufA  = (float*)(ws + 2001408);   // [6400000]
    float* bufH  = (float*)(ws + 8401408);   // [6400000]
    int* partials = ws + 14801408;           // [256]

    hipMemsetAsync(row_cnt, 0, 100352 * sizeof(int), stream);

    k_deg_f<<<NCHUNK * RNG, 256, 0, stream>>>(dst, row_cnt);
    k_scan1<<<98, 256, 0, stream>>>(row_cnt, row_ptr, partials, dinv);
    k_scan2<<<1, 256, 0, stream>>>(partials, 98);
    k_scan3<<<(N_NODES + 255) / 256, 256, 0, stream>>>(row_ptr, cursor, partials);
    k_fill_f<<<NCHUNK * RNG, 256, 0, stream>>>(src, dst, cursor, col);

    // layer 1: x(20) -> y1 (bufA)
    k_gemm1<<<N_NODES / 4, 256, 0, stream>>>(x, W1, dinv, bufA);
    // layer 1 agg fused with layer 2 gemm: bufA -> bufH (= y2)
    k_aggemm<<<N_NODES / 4, 256, 0, stream>>>(bufA, row_ptr, col, dinv, b1, W2, bufH);
    // layer 2 agg fused with layer 3 gemm: bufH -> bufA (= y3)
    k_aggemm<<<N_NODES / 4, 256, 0, stream>>>(bufH, row_ptr, col, dinv, b2, W3, bufA);
    // layer 3 agg: bufA -> bufH (= h3)
    k_agg<<<N_NODES / 4, 256, 0, stream>>>(bufA, row_ptr, col, dinv, b3, bufH);

    // pool + head
    k_pool_head<<<N_GRAPHS, 64, 0, stream>>>(bufH, batch, lw1, lb1, lw2, lb2, out);
}